// Round 1
// baseline (421.174 us; speedup 1.0000x reference)
//
#include <hip/hip_runtime.h>
#include <cstdint>
#include <cstddef>
#include <type_traits>

// Problem constants
// B=4, Q=64, S=64, T=128, HID=768, NH=12, HD=64
#define HID 768
#define NB 4
#define NQ 64
#define NS 64
#define NT 128
#define NHEAD 12
#define HD 64

typedef __attribute__((ext_vector_type(8))) short bf16x8;   // 8 bf16 in 4 VGPRs
typedef __attribute__((ext_vector_type(4))) float f32x4;

__device__ __forceinline__ unsigned short f2bf(float f) {
    union { float f; uint32_t u; } c; c.f = f;
    uint32_t x = c.u;
    uint32_t r = (x + 0x7FFFu + ((x >> 16) & 1u)) >> 16;
    return (unsigned short)r;
}

__device__ __forceinline__ f32x4 mfma16(bf16x8 a, bf16x8 b, f32x4 c) {
    return __builtin_amdgcn_mfma_f32_16x16x32_bf16(a, b, c, 0, 0, 0);
}

__device__ __forceinline__ void gload_lds16(const void* g, void* l) {
    __builtin_amdgcn_global_load_lds(
        (const __attribute__((address_space(1))) unsigned int*)g,
        (__attribute__((address_space(3))) unsigned int*)l, 16, 0, 0);
}

// ---------------------------------------------------------------- casts
__global__ __launch_bounds__(256) void cast4_f32_bf16(const float* __restrict__ in,
                                                      unsigned short* __restrict__ out, int n4) {
    int i = blockIdx.x * 256 + threadIdx.x;
    if (i < n4) {
        float4 v = ((const float4*)in)[i];
        ushort4 o;
        o.x = f2bf(v.x); o.y = f2bf(v.y); o.z = f2bf(v.z); o.w = f2bf(v.w);
        ((ushort4*)out)[i] = o;
    }
}

// Wt[n][k] = W[k][n], 768x768, bf16 out. grid=576, block=256 (32x8)
__global__ __launch_bounds__(256) void transpose_cast_768(const float* __restrict__ W,
                                                          unsigned short* __restrict__ Wt) {
    __shared__ float t[32][33];
    int bx = blockIdx.x % 24, by = blockIdx.x / 24;
    int n0 = bx * 32, k0 = by * 32;
    int tx = threadIdx.x & 31, ty = threadIdx.x >> 5;
#pragma unroll
    for (int i = 0; i < 4; ++i)
        t[ty + i * 8][tx] = W[(size_t)(k0 + ty + i * 8) * 768 + n0 + tx];
    __syncthreads();
#pragma unroll
    for (int i = 0; i < 4; ++i)
        Wt[(size_t)(n0 + ty + i * 8) * 768 + k0 + tx] = f2bf(t[tx][ty + i * 8]);
}

// ---------------------------------------------------------------- GEMM
// C[M,768] = A[M,768](bf16) * Bt[768,768]^T(bf16, Bt[n][k]) + bias, m97 structure:
// 128x128 tile, BK=32, 4 waves (2x2), global_load_lds width 16, linear LDS.
template <typename CT>
__global__ __launch_bounds__(256) void gemm_bt_768(const unsigned short* __restrict__ A,
                                                   const unsigned short* __restrict__ Bt,
                                                   const float* __restrict__ bias,
                                                   CT* __restrict__ C, int M) {
    constexpr int K = 768, N = 768;
    __shared__ __align__(16) unsigned short As[128 * 32];
    __shared__ __align__(16) unsigned short Bs[128 * 32];

    int tid = threadIdx.x;
    int w = tid >> 6, l = tid & 63;
    int li = l & 15, g = l >> 4;
    int wm = w >> 1, wn = w & 1;           // 2x2 wave grid, each wave 64x64
    int nb = blockIdx.x % (N / 128);
    int mb = blockIdx.x / (N / 128);

    const unsigned short* Ab = A + (size_t)mb * 128 * K;
    const unsigned short* Bb = Bt + (size_t)nb * 128 * K;

    // staging chunk mapping: chunk = w*128 + i*64 + l -> row=chunk>>2, kc=chunk&3
    int ch0 = w * 128 + l, ch1 = w * 128 + 64 + l;
    int r0 = ch0 >> 2, c0 = ch0 & 3;
    int r1 = ch1 >> 2, c1 = ch1 & 3;
    char* lA0 = (char*)As + w * 2048;
    char* lA1 = (char*)As + w * 2048 + 1024;
    char* lB0 = (char*)Bs + w * 2048;
    char* lB1 = (char*)Bs + w * 2048 + 1024;

    f32x4 acc[4][4];
#pragma unroll
    for (int mi = 0; mi < 4; ++mi)
#pragma unroll
        for (int ni = 0; ni < 4; ++ni) acc[mi][ni] = (f32x4){0.f, 0.f, 0.f, 0.f};

    for (int kt = 0; kt < K / 32; ++kt) {
        int k0 = kt * 32;
        __syncthreads();   // previous iter's ds_reads complete
        gload_lds16(Ab + (size_t)r0 * K + k0 + c0 * 8, lA0);
        gload_lds16(Ab + (size_t)r1 * K + k0 + c1 * 8, lA1);
        gload_lds16(Bb + (size_t)r0 * K + k0 + c0 * 8, lB0);
        gload_lds16(Bb + (size_t)r1 * K + k0 + c1 * 8, lB1);
        __syncthreads();   // vmcnt(0) drain -> tiles visible

        bf16x8 af[4], bb[4];
#pragma unroll
        for (int mi = 0; mi < 4; ++mi)
            af[mi] = *(const bf16x8*)&As[(wm * 64 + mi * 16 + li) * 32 + g * 8];
#pragma unroll
        for (int ni = 0; ni < 4; ++ni)
            bb[ni] = *(const bf16x8*)&Bs[(wn * 64 + ni * 16 + li) * 32 + g * 8];
#pragma unroll
        for (int mi = 0; mi < 4; ++mi)
#pragma unroll
            for (int ni = 0; ni < 4; ++ni)
                acc[mi][ni] = mfma16(af[mi], bb[ni], acc[mi][ni]);
    }

    int rowb = mb * 128 + wm * 64;
    int colb = nb * 128 + wn * 64;
#pragma unroll
    for (int ni = 0; ni < 4; ++ni) {
        float bv = bias[colb + ni * 16 + li];
        int col = colb + ni * 16 + li;
#pragma unroll
        for (int mi = 0; mi < 4; ++mi) {
#pragma unroll
            for (int r = 0; r < 4; ++r) {
                int row = rowb + mi * 16 + g * 4 + r;
                float v = acc[mi][ni][r] + bv;
                if constexpr (std::is_same_v<CT, unsigned short>)
                    C[(size_t)row * N + col] = f2bf(v);
                else
                    C[(size_t)row * N + col] = v;
            }
        }
    }
}

// ---------------------------------------------------------------- attention
// One block per (b,s,h). 4 waves, each owns 16 q-rows.
// scores[64,128] = Q Kt^T * SCALE + mask*(-1e4); softmax over t; out = alpha V.
__global__ __launch_bounds__(256) void attn_bsh(const unsigned short* __restrict__ Qp,
                                                const unsigned short* __restrict__ Kb,
                                                const unsigned short* __restrict__ Vb,
                                                const float* __restrict__ mask,
                                                unsigned short* __restrict__ res) {
    // LDS: K[128][72], VT[64][136], QA union {Q[64][72], alpha[64][136]}
    __shared__ __align__(16) unsigned short Kl[128 * 72];
    __shared__ __align__(16) unsigned short VT[64 * 136];
    __shared__ __align__(16) unsigned short QA[64 * 136];

    int bid = blockIdx.x;
    int h = bid % NHEAD;
    int bs = bid / NHEAD;
    int s = bs % NS;
    int b = bs / NS;

    int tid = threadIdx.x, w = tid >> 6, l = tid & 63;
    int li = l & 15, g = l >> 4;

    // ---- stage Q (64 rows x 8 chunks of 8 bf16)
    const unsigned short* Qg = Qp + (size_t)(b * NQ) * HID + h * HD;
#pragma unroll
    for (int it = 0; it < 2; ++it) {
        int idx = it * 256 + tid;
        int q = idx >> 3, c = idx & 7;
        *(uint4*)&QA[q * 72 + c * 8] = *(const uint4*)&Qg[(size_t)q * HID + c * 8];
    }
    // ---- stage K
    const unsigned short* Kg = Kb + ((size_t)(b * NS + s) * NT) * HID + h * HD;
#pragma unroll
    for (int it = 0; it < 4; ++it) {
        int idx = it * 256 + tid;
        int t = idx >> 3, c = idx & 7;
        *(uint4*)&Kl[t * 72 + c * 8] = *(const uint4*)&Kg[(size_t)t * HID + c * 8];
    }
    // ---- stage V transposed: VT[d][t]
    const unsigned short* Vg = Vb + ((size_t)(b * NS + s) * NT) * HID + h * HD;
#pragma unroll
    for (int it = 0; it < 4; ++it) {
        int idx = it * 256 + tid;
        int t = idx >> 3, c = idx & 7;
        uint4 raw = *(const uint4*)&Vg[(size_t)t * HID + c * 8];
        const unsigned short* e = (const unsigned short*)&raw;
#pragma unroll
        for (int j = 0; j < 8; ++j) VT[(c * 8 + j) * 136 + t] = e[j];
    }
    __syncthreads();

    // ---- scores: wave w handles q rows [w*16, w*16+16)
    bf16x8 aq0 = *(const bf16x8*)&QA[(w * 16 + li) * 72 + g * 8];
    bf16x8 aq1 = *(const bf16x8*)&QA[(w * 16 + li) * 72 + 32 + g * 8];
    f32x4 sc[8];
#pragma unroll
    for (int tc = 0; tc < 8; ++tc) {
        sc[tc] = (f32x4){0.f, 0.f, 0.f, 0.f};
        bf16x8 b0 = *(const bf16x8*)&Kl[(tc * 16 + li) * 72 + g * 8];
        sc[tc] = mfma16(aq0, b0, sc[tc]);
        bf16x8 b1 = *(const bf16x8*)&Kl[(tc * 16 + li) * 72 + 32 + g * 8];
        sc[tc] = mfma16(aq1, b1, sc[tc]);
    }

    // ---- softmax (rows live on 16-lane groups; C layout col=li, row=g*4+r)
    const float* mrow = mask + (size_t)(b * NS + s) * NT;
    float mv[8];
#pragma unroll
    for (int tc = 0; tc < 8; ++tc) mv[tc] = mrow[tc * 16 + li] * -10000.0f;

    float p[8][4];
    float rmax[4] = {-3.0e38f, -3.0e38f, -3.0e38f, -3.0e38f};
#pragma unroll
    for (int tc = 0; tc < 8; ++tc)
#pragma unroll
        for (int r = 0; r < 4; ++r) {
            float v = sc[tc][r] * 0.125f + mv[tc];
            p[tc][r] = v;
            rmax[r] = fmaxf(rmax[r], v);
        }
#pragma unroll
    for (int r = 0; r < 4; ++r)
#pragma unroll
        for (int m = 1; m < 16; m <<= 1)
            rmax[r] = fmaxf(rmax[r], __shfl_xor(rmax[r], m, 64));

    float rsum[4] = {0.f, 0.f, 0.f, 0.f};
#pragma unroll
    for (int tc = 0; tc < 8; ++tc)
#pragma unroll
        for (int r = 0; r < 4; ++r) {
            float e = __expf(p[tc][r] - rmax[r]);
            p[tc][r] = e;
            rsum[r] += e;
        }
#pragma unroll
    for (int r = 0; r < 4; ++r)
#pragma unroll
        for (int m = 1; m < 16; m <<= 1)
            rsum[r] += __shfl_xor(rsum[r], m, 64);
    float rinv[4];
#pragma unroll
    for (int r = 0; r < 4; ++r) rinv[r] = 1.0f / rsum[r];

    __syncthreads();   // all waves done reading QA-as-Q
#pragma unroll
    for (int tc = 0; tc < 8; ++tc)
#pragma unroll
        for (int r = 0; r < 4; ++r)
            QA[(w * 16 + g * 4 + r) * 136 + tc * 16 + li] = f2bf(p[tc][r] * rinv[r]);
    __syncthreads();

    // ---- PV: out[16,64] per wave, k=t in 4 steps of 32
    bf16x8 pa[4];
#pragma unroll
    for (int ks = 0; ks < 4; ++ks)
        pa[ks] = *(const bf16x8*)&QA[(w * 16 + li) * 136 + ks * 32 + g * 8];
    f32x4 o[4];
#pragma unroll
    for (int dc = 0; dc < 4; ++dc) {
        o[dc] = (f32x4){0.f, 0.f, 0.f, 0.f};
#pragma unroll
        for (int ks = 0; ks < 4; ++ks) {
            bf16x8 bv = *(const bf16x8*)&VT[(dc * 16 + li) * 136 + ks * 32 + g * 8];
            o[dc] = mfma16(pa[ks], bv, o[dc]);
        }
    }

    // ---- store res[b,q,s,h*64+d] (bf16)
#pragma unroll
    for (int dc = 0; dc < 4; ++dc) {
#pragma unroll
        for (int r = 0; r < 4; ++r) {
            int q = w * 16 + g * 4 + r;
            int d = dc * 16 + li;
            res[((size_t)(b * NQ + q) * NS + s) * HID + h * HD + d] = f2bf(o[dc][r]);
        }
    }
}

// ---------------------------------------------------------------- LayerNorm
// one wave per row of 768 fp32; 4 rows per block
__global__ __launch_bounds__(256) void ln_768(const float* __restrict__ X,
                                              const float* __restrict__ gamma,
                                              const float* __restrict__ beta,
                                              float* __restrict__ out) {
    int w = threadIdx.x >> 6, l = threadIdx.x & 63;
    size_t row = (size_t)blockIdx.x * 4 + w;
    const float4* xr = (const float4*)(X + row * 768);
    float4 v[3];
    float s = 0.f, sq = 0.f;
#pragma unroll
    for (int j = 0; j < 3; ++j) {
        v[j] = xr[l + j * 64];
        s += v[j].x + v[j].y + v[j].z + v[j].w;
        sq += v[j].x * v[j].x + v[j].y * v[j].y + v[j].z * v[j].z + v[j].w * v[j].w;
    }
#pragma unroll
    for (int m = 32; m >= 1; m >>= 1) {
        s += __shfl_xor(s, m, 64);
        sq += __shfl_xor(sq, m, 64);
    }
    float mu = s * (1.0f / 768.0f);
    float var = sq * (1.0f / 768.0f) - mu * mu;
    float rstd = rsqrtf(fmaxf(var, 0.0f) + 1e-12f);
    const float4* g4 = (const float4*)gamma;
    const float4* b4 = (const float4*)beta;
    float4* o4 = (float4*)(out + row * 768);
#pragma unroll
    for (int j = 0; j < 3; ++j) {
        float4 gg = g4[l + j * 64], bb = b4[l + j * 64];
        float4 r;
        r.x = (v[j].x - mu) * rstd * gg.x + bb.x;
        r.y = (v[j].y - mu) * rstd * gg.y + bb.y;
        r.z = (v[j].z - mu) * rstd * gg.z + bb.z;
        r.w = (v[j].w - mu) * rstd * gg.w + bb.w;
        o4[l + j * 64] = r;
    }
}

// ---------------------------------------------------------------- launch
extern "C" void kernel_launch(void* const* d_in, const int* in_sizes, int n_in,
                              void* d_out, int out_size, void* d_ws, size_t ws_size,
                              hipStream_t stream) {
    const float* ini_q = (const float*)d_in[0];
    const float* ini_k = (const float*)d_in[1];
    const float* mask  = (const float*)d_in[2];
    const float* Wq = (const float*)d_in[3];
    const float* bq = (const float*)d_in[4];
    const float* Wk = (const float*)d_in[5];
    const float* bk = (const float*)d_in[6];
    const float* Wv = (const float*)d_in[7];
    const float* bv = (const float*)d_in[8];
    const float* Wo = (const float*)d_in[9];
    const float* bo = (const float*)d_in[10];
    const float* gamma = (const float*)d_in[11];
    const float* beta  = (const float*)d_in[12];
    float* out = (float*)d_out;

    // workspace layout (bytes)
    constexpr size_t SZ_X = (size_t)32768 * 768 * 2;  // 50331648 (== res2 fp32 size)
    constexpr size_t SZ_R = (size_t)16384 * 768 * 2;  // 25165824
    constexpr size_t SZ_Q = (size_t)256 * 768 * 2;    // 393216
    constexpr size_t SZ_W = (size_t)768 * 768 * 2;    // 1179648

    char* base = (char*)d_ws;
    unsigned short* X   = (unsigned short*)(base);                 // ini_k bf16 [32768,768]
    unsigned short* Kb  = (unsigned short*)(base + SZ_X);
    unsigned short* Vb  = (unsigned short*)(base + 2 * SZ_X);
    unsigned short* res = (unsigned short*)(base + 3 * SZ_X);      // [16384,768] bf16
    unsigned short* Xq  = (unsigned short*)(base + 3 * SZ_X + SZ_R);
    unsigned short* Qp  = (unsigned short*)(base + 3 * SZ_X + SZ_R + SZ_Q);
    unsigned short* WqT = (unsigned short*)(base + 3 * SZ_X + SZ_R + 2 * SZ_Q);
    unsigned short* WkT = (unsigned short*)((char*)WqT + SZ_W);
    unsigned short* WvT = (unsigned short*)((char*)WqT + 2 * SZ_W);
    unsigned short* WoT = (unsigned short*)((char*)WqT + 3 * SZ_W);
    float* res2 = (float*)(base);                                  // aliases X (X dead by then)

    // 1) casts
    cast4_f32_bf16<<<24576, 256, 0, stream>>>(ini_k, X, 6291456);   // 4*64*128*768/4
    cast4_f32_bf16<<<192, 256, 0, stream>>>(ini_q, Xq, 49152);      // 4*64*768/4
    transpose_cast_768<<<576, 256, 0, stream>>>(Wq, WqT);
    transpose_cast_768<<<576, 256, 0, stream>>>(Wk, WkT);
    transpose_cast_768<<<576, 256, 0, stream>>>(Wv, WvT);
    transpose_cast_768<<<576, 256, 0, stream>>>(Wo, WoT);

    // 2) projections
    gemm_bt_768<unsigned short><<<dim3(2 * 6), 256, 0, stream>>>(Xq, WqT, bq, Qp, 256);
    gemm_bt_768<unsigned short><<<dim3(256 * 6), 256, 0, stream>>>(X, WkT, bk, Kb, 32768);
    gemm_bt_768<unsigned short><<<dim3(256 * 6), 256, 0, stream>>>(X, WvT, bv, Vb, 32768);

    // 3) attention
    attn_bsh<<<dim3(NB * NS * NHEAD), 256, 0, stream>>>(Qp, Kb, Vb, mask, res);

    // 4) output projection (fp32 out) + LayerNorm
    gemm_bt_768<float><<<dim3(128 * 6), 256, 0, stream>>>(res, WoT, bo, res2, 16384);
    ln_768<<<dim3(4096), 256, 0, stream>>>(res2, gamma, beta, out);
}